// Round 5
// baseline (965.946 us; speedup 1.0000x reference)
//
#include <hip/hip_runtime.h>
#include <hip/hip_bf16.h>
#include <math.h>

#define NN 10000
#define EE 80000
#define SDIM 18
#define HID 1024
#define NLAYERS 4
#define GHID 256

typedef __bf16 bf16;
typedef __bf16 bf16x8 __attribute__((ext_vector_type(8)));
typedef __bf16 bf16x4 __attribute__((ext_vector_type(4)));
typedef float f32x4 __attribute__((ext_vector_type(4)));

#define AS1C(p) ((const __attribute__((address_space(1))) void*)(p))
#define AS3(p)  ((__attribute__((address_space(3))) void*)(p))

// LDS plane geometry: 4 planes per operand, each 128 rows x 16B, padded +16B
#define PLANE_ELEMS 1032  // (2048 + 16) / 2

// ---------------- zero fill (ints) ----------------
__global__ void zeroi_kernel(int* __restrict__ p, int n) {
    int i = blockIdx.x * 256 + threadIdx.x;
    if (i < n) p[i] = 0;
}

// ---------------- CSR build: count ----------------
__global__ void count_kernel(const int* __restrict__ ei, int* __restrict__ cnt) {
    int e = blockIdx.x * 256 + threadIdx.x;
    if (e < EE) atomicAdd(&cnt[ei[EE + e]], 1);
}

// ---------------- CSR build: exclusive scan (single block) ----------------
__global__ __launch_bounds__(256) void scan_kernel(const int* __restrict__ cnt,
                                                   int* __restrict__ offs,
                                                   int* __restrict__ cursor,
                                                   float* __restrict__ degF) {
    const int CH = 40;  // 256*40 = 10240 >= NN
    __shared__ int partial[256];
    int t = threadIdx.x;
    int base = t * CH;
    int local[CH];
    int sum = 0;
#pragma unroll
    for (int i = 0; i < CH; ++i) {
        int idx = base + i;
        int v = (idx < NN) ? cnt[idx] : 0;
        local[i] = sum;
        sum += v;
    }
    partial[t] = sum;
    __syncthreads();
    for (int off = 1; off < 256; off <<= 1) {
        int v = (t >= off) ? partial[t - off] : 0;
        __syncthreads();
        partial[t] += v;
        __syncthreads();
    }
    int excl = (t == 0) ? 0 : partial[t - 1];
#pragma unroll
    for (int i = 0; i < CH; ++i) {
        int idx = base + i;
        if (idx < NN) {
            int o = excl + local[i];
            offs[idx] = o;
            cursor[idx] = o;
            degF[idx] = (float)cnt[idx];
        }
    }
    if (t == 255) offs[NN] = partial[255];
}

// ---------------- CSR build: scatter edge sources ----------------
__global__ void scatter_kernel(const int* __restrict__ ei, int* __restrict__ cursor,
                               int* __restrict__ esrc) {
    int e = blockIdx.x * 256 + threadIdx.x;
    if (e < EE) {
        int dst = ei[EE + e];
        int pos = atomicAdd(&cursor[dst], 1);
        esrc[pos] = ei[e];
    }
}

// ---------------- fused W1 transpose: WT[l] = [(W1top-W1bot)^T ; W1bot^T] bf16 ----------------
__global__ __launch_bounds__(256) void tconvW1_kernel(const float* __restrict__ W1,
                                                      bf16* __restrict__ WT) {
    __shared__ float td[32][33];
    __shared__ float tb[32][33];
    const size_t H2 = (size_t)HID * HID;
    const float* s = W1 + (size_t)blockIdx.z * 2 * H2;
    bf16* d = WT + (size_t)blockIdx.z * 2 * H2;
    int bx = blockIdx.x * 32;  // col (n) base
    int by = blockIdx.y * 32;  // row (k) base
    int tx = threadIdx.x, ty = threadIdx.y;  // (32,8)
#pragma unroll
    for (int r = 0; r < 4; ++r) {
        int row = by + ty + r * 8;
        float vt = s[(size_t)row * HID + bx + tx];
        float vb = s[H2 + (size_t)row * HID + bx + tx];
        td[ty + r * 8][tx] = vt - vb;
        tb[ty + r * 8][tx] = vb;
    }
    __syncthreads();
#pragma unroll
    for (int r = 0; r < 4; ++r) {
        int orow = bx + ty + r * 8;  // n index
        d[(size_t)orow * HID + by + tx] = (bf16)td[tx][ty + r * 8];
        d[(size_t)(HID + orow) * HID + by + tx] = (bf16)tb[tx][ty + r * 8];
    }
}

// ---------------- generic transpose+convert: dst[N][M] bf16 = src[M][N] fp32 ----------------
__global__ __launch_bounds__(256) void tconv_kernel(const float* __restrict__ src, long sstride,
                                                    bf16* __restrict__ dst, long dstride,
                                                    int M, int N) {
    __shared__ float t[32][33];
    const float* s = src + (size_t)blockIdx.z * sstride;
    bf16* d = dst + (size_t)blockIdx.z * dstride;
    int bx = blockIdx.x * 32;
    int by = blockIdx.y * 32;
    int tx = threadIdx.x, ty = threadIdx.y;
#pragma unroll
    for (int r = 0; r < 4; ++r) {
        int row = by + ty + r * 8;
        t[ty + r * 8][tx] = s[(size_t)row * N + bx + tx];
    }
    __syncthreads();
#pragma unroll
    for (int r = 0; r < 4; ++r) {
        int orow = bx + ty + r * 8;
        d[(size_t)orow * M + by + tx] = (bf16)t[tx][ty + r * 8];
    }
}

// ---------------- swt[32][1024] bf16 = sw[1024][18]^T zero-padded ----------------
__global__ void swt_kernel(const float* __restrict__ sw, bf16* __restrict__ swt) {
    int i = blockIdx.x * 256 + threadIdx.x;  // 32*1024
    int n = i >> 10, k = i & 1023;
    swt[i] = (bf16)(n < SDIM ? sw[k * SDIM + n] : 0.f);
}

// ---------------- combined bias cb[l][2048] = [b1[l] ; 0] ----------------
__global__ void bias2_kernel(const float* __restrict__ b1, float* __restrict__ cb) {
    int i = blockIdx.x * 256 + threadIdx.x;  // 4*2048
    int l = i >> 11, c = i & 2047;
    cb[i] = (c < HID) ? b1[l * HID + c] : 0.f;
}

// ---------------- h0 = sin(x@pw)*cos(x@pw) -> bf16 ----------------
__global__ __launch_bounds__(256) void proj_kernel(const float* __restrict__ x,
                                                   const float* __restrict__ pw,
                                                   bf16* __restrict__ hb) {
    int row = blockIdx.y;
    int col = blockIdx.x * 256 + threadIdx.x;
    __shared__ float xr[SDIM];
    if (threadIdx.x < SDIM) xr[threadIdx.x] = x[row * SDIM + threadIdx.x];
    __syncthreads();
    float acc = 0.f;
#pragma unroll
    for (int k = 0; k < SDIM; ++k) acc += xr[k] * pw[k * HID + col];
    hb[(size_t)row * HID + col] = (bf16)(sinf(acc) * cosf(acc));
}

// ---------------- bf16 MFMA GEMM: C = act(A @ Bt^T + rs*bias) ----------------
// m97 structure + plane-major LDS staging (bank-conflict-free ds_read_b128) +
// GROUP_M=8 block swizzle for per-XCD A-tile L2 reuse.
template <int RELU, int HAS_BIAS, int HAS_RS, int WF32, int WB16>
__global__ __launch_bounds__(256) void mgemm_kernel(const bf16* __restrict__ A,
                                                    const bf16* __restrict__ Bt,
                                                    float* __restrict__ C,
                                                    bf16* __restrict__ Cb,
                                                    const float* __restrict__ bias,
                                                    const float* __restrict__ rowscale,
                                                    int M, int N, int K) {
    __shared__ __align__(16) bf16 As[4 * PLANE_ELEMS];
    __shared__ __align__(16) bf16 Bs[4 * PLANE_ELEMS];
    const int tid = threadIdx.x;

    // ---- grouped block swizzle: 8 row-tiles per column sweep ----
    const int num_n = gridDim.x, num_m = gridDim.y;
    int bid = blockIdx.x + blockIdx.y * num_n;
    const int GROUP = 8;
    int width = GROUP * num_n;
    int group = bid / width;
    int rem = bid - group * width;
    int rows_ing = num_m - group * GROUP;
    rows_ing = rows_ing < GROUP ? rows_ing : GROUP;
    int by = group * GROUP + rem % rows_ing;
    int bx = rem / rows_ing;
    const int m0 = by * 128;
    const int n0 = bx * 128;

    const int wave = tid >> 6;
    const int wr = (wave >> 1) * 64, wc = (wave & 1) * 64;
    const int lane = tid & 63;
    const int quad = lane >> 4, r15 = lane & 15;

    f32x4 acc[4][4] = {};

    // ---- staging: wave w stages rows (w&1)*64+lane for ksegs (w>>1) and 2+(w>>1) ----
    const int rA = (wave & 1) * 64 + lane;     // tile row 0..127
    const int ks1 = wave >> 1;                 // kseg 0/1
    const int ks2 = 2 + (wave >> 1);           // kseg 2/3
    int grA = m0 + rA; grA = grA < M ? grA : M - 1;
    const int grB = n0 + rA;                   // N is always a multiple of 128 here
    const bf16* gA1 = A + (size_t)grA * K + ks1 * 8;
    const bf16* gA2 = A + (size_t)grA * K + ks2 * 8;
    const bf16* gB1 = Bt + (size_t)grB * K + ks1 * 8;
    const bf16* gB2 = Bt + (size_t)grB * K + ks2 * 8;
    // wave-uniform LDS bases (HW adds lane*16B): plane p at p*PLANE_ELEMS, half at (w&1)*512
    bf16* lA1 = As + ks1 * PLANE_ELEMS + (wave & 1) * 512;
    bf16* lA2 = As + ks2 * PLANE_ELEMS + (wave & 1) * 512;
    bf16* lB1 = Bs + ks1 * PLANE_ELEMS + (wave & 1) * 512;
    bf16* lB2 = Bs + ks2 * PLANE_ELEMS + (wave & 1) * 512;

    for (int k0 = 0; k0 < K; k0 += 32) {
        __syncthreads();
        __builtin_amdgcn_global_load_lds(AS1C(gA1 + k0), AS3(lA1), 16, 0, 0);
        __builtin_amdgcn_global_load_lds(AS1C(gA2 + k0), AS3(lA2), 16, 0, 0);
        __builtin_amdgcn_global_load_lds(AS1C(gB1 + k0), AS3(lB1), 16, 0, 0);
        __builtin_amdgcn_global_load_lds(AS1C(gB2 + k0), AS3(lB2), 16, 0, 0);
        __syncthreads();
        bf16x8 af[4], bfr[4];
#pragma unroll
        for (int i = 0; i < 4; ++i)
            af[i] = *(const bf16x8*)(As + quad * PLANE_ELEMS + (wr + i * 16 + r15) * 8);
#pragma unroll
        for (int j = 0; j < 4; ++j)
            bfr[j] = *(const bf16x8*)(Bs + quad * PLANE_ELEMS + (wc + j * 16 + r15) * 8);
#pragma unroll
        for (int i = 0; i < 4; ++i)
#pragma unroll
            for (int j = 0; j < 4; ++j)
                acc[i][j] = __builtin_amdgcn_mfma_f32_16x16x32_bf16(af[i], bfr[j], acc[i][j], 0, 0, 0);
    }

    // epilogue: C/D layout col=lane&15, row=quad*4+reg (m89-verified)
#pragma unroll
    for (int i = 0; i < 4; ++i) {
#pragma unroll
        for (int r = 0; r < 4; ++r) {
            int grow = m0 + wr + i * 16 + quad * 4 + r;
            if (grow >= M) continue;
            float rs = HAS_RS ? rowscale[grow] : 1.f;
#pragma unroll
            for (int j = 0; j < 4; ++j) {
                int gcol = n0 + wc + j * 16 + r15;
                float v = acc[i][j][r];
                if (HAS_BIAS) v += rs * bias[gcol];
                if (RELU) v = fmaxf(v, 0.f);
                if (WF32) C[(size_t)grow * N + gcol] = v;
                if (WB16) Cb[(size_t)grow * N + gcol] = (bf16)v;
            }
        }
    }
}

// ---------------- CSR aggregation over combined CB[node][2048] = [Cn ; Bn] ----------------
__global__ __launch_bounds__(256) void gather_kernel(const int* __restrict__ offs,
                                                     const int* __restrict__ esrc,
                                                     const bf16* __restrict__ CB,
                                                     bf16* __restrict__ Sb) {
    int node = blockIdx.x;
    int c = threadIdx.x * 4;
    int k0 = offs[node], k1 = offs[node + 1];
    bf16x4 cv = *(const bf16x4*)(CB + (size_t)node * 2048 + c);
    float cx = (float)cv.x, cy = (float)cv.y, cz = (float)cv.z, cw = (float)cv.w;
    float ax = 0.f, ay = 0.f, az = 0.f, aw = 0.f;
    for (int k = k0; k < k1; ++k) {
        int s = esrc[k];
        bf16x4 bv = *(const bf16x4*)(CB + (size_t)s * 2048 + 1024 + c);
        ax += fmaxf(cx + (float)bv.x, 0.f);
        ay += fmaxf(cy + (float)bv.y, 0.f);
        az += fmaxf(cz + (float)bv.z, 0.f);
        aw += fmaxf(cw + (float)bv.w, 0.f);
    }
    bf16x4 o;
    o.x = (bf16)ax; o.y = (bf16)ay; o.z = (bf16)az; o.w = (bf16)aw;
    *(bf16x4*)(Sb + (size_t)node * HID + c) = o;
}

// ---------------- stable head via MFMA: out[16 rows][18] = hb_tile @ swt^T + sb ----------------
__global__ __launch_bounds__(64) void stable_mfma_kernel(const bf16* __restrict__ hb,
                                                         const bf16* __restrict__ swt,
                                                         const float* __restrict__ sb,
                                                         float* __restrict__ out) {
    int m0 = blockIdx.x * 16;  // NN = 625*16 exact
    int lane = threadIdx.x;
    int quad = lane >> 4, r15 = lane & 15;
    f32x4 acc0 = {}, acc1 = {};
    const bf16* arow = hb + (size_t)(m0 + r15) * HID + quad * 8;
    const bf16* b0 = swt + (size_t)r15 * HID + quad * 8;
    const bf16* b1p = swt + (size_t)(16 + r15) * HID + quad * 8;
    for (int k0 = 0; k0 < HID; k0 += 32) {
        bf16x8 af = *(const bf16x8*)(arow + k0);
        bf16x8 bf0 = *(const bf16x8*)(b0 + k0);
        bf16x8 bf1 = *(const bf16x8*)(b1p + k0);
        acc0 = __builtin_amdgcn_mfma_f32_16x16x32_bf16(af, bf0, acc0, 0, 0, 0);
        acc1 = __builtin_amdgcn_mfma_f32_16x16x32_bf16(af, bf1, acc1, 0, 0, 0);
    }
#pragma unroll
    for (int r = 0; r < 4; ++r) {
        int grow = m0 + quad * 4 + r;
        out[(size_t)grow * SDIM + r15] = acc0[r] + sb[r15];
        if (r15 < 2) out[(size_t)grow * SDIM + 16 + r15] = acc1[r] + sb[16 + r15];
    }
}

// ---------------- ghost head stage 2: sigmoid(g1 @ gw2 + gb2) ----------------
__global__ __launch_bounds__(256) void ghost_kernel(const float* __restrict__ g1,
                                                    const float* __restrict__ gw2,
                                                    const float* __restrict__ gb2,
                                                    float* __restrict__ out) {
    int row = blockIdx.x;
    int t = threadIdx.x;
    float v = g1[(size_t)row * GHID + t] * gw2[t];
#pragma unroll
    for (int o = 32; o > 0; o >>= 1) v += __shfl_down(v, o, 64);
    __shared__ float red[4];
    if ((t & 63) == 0) red[t >> 6] = v;
    __syncthreads();
    if (t == 0) {
        float s = red[0] + red[1] + red[2] + red[3] + gb2[0];
        out[row] = 1.f / (1.f + expf(-s));
    }
}

extern "C" void kernel_launch(void* const* d_in, const int* in_sizes, int n_in,
                              void* d_out, int out_size, void* d_ws, size_t ws_size,
                              hipStream_t stream) {
    const float* x   = (const float*)d_in[0];
    const int*   ei  = (const int*)d_in[1];
    const float* pw  = (const float*)d_in[2];
    const float* W1  = (const float*)d_in[3];
    const float* b1  = (const float*)d_in[4];
    const float* W2  = (const float*)d_in[5];
    const float* b2  = (const float*)d_in[6];
    const float* gw1 = (const float*)d_in[7];
    const float* gb1 = (const float*)d_in[8];
    const float* gw2 = (const float*)d_in[9];
    const float* gb2 = (const float*)d_in[10];
    const float* sw  = (const float*)d_in[11];
    const float* sb  = (const float*)d_in[12];

    float* out    = (float*)d_out;
    float* ghost  = out;                  // [N,1]
    float* stable = out + NN;             // [N,18]
    float* h      = out + NN + NN * SDIM; // [N,HID] fp32 (final h output)

    const size_t H2 = (size_t)HID * HID;
    float* ws   = (float*)d_ws;
    float* g1   = ws;                                  // NN*GHID fp32
    float* degF = g1 + (size_t)NN * GHID;              // NN
    float* cb   = degF + NN;                           // 4*2048 fp32
    bf16* hb    = (bf16*)(cb + 4 * 2048);              // NN*HID
    bf16* Sb    = hb + (size_t)NN * HID;               // NN*HID
    bf16* CB    = Sb + (size_t)NN * HID;               // NN*2048
    bf16* WT    = CB + (size_t)NN * 2048;              // 4 * 2*H2  ([Wd;Wb]^T per layer)
    bf16* W2t   = WT + 8 * H2;                         // 4*H2
    bf16* gw1t  = W2t + 4 * H2;                        // GHID*HID
    bf16* swt   = gw1t + (size_t)GHID * HID;           // 32*1024
    int*  cnt    = (int*)(swt + 32 * 1024);
    int*  offs   = cnt + NN;
    int*  cursor = offs + NN + 1;
    int*  esrc   = cursor + NN;

    // ---- CSR build ----
    zeroi_kernel<<<dim3((NN + 255) / 256), 256, 0, stream>>>(cnt, NN);
    count_kernel<<<dim3((EE + 255) / 256), 256, 0, stream>>>(ei, cnt);
    scan_kernel<<<dim3(1), 256, 0, stream>>>(cnt, offs, cursor, degF);
    scatter_kernel<<<dim3((EE + 255) / 256), 256, 0, stream>>>(ei, cursor, esrc);

    // ---- weight prep ----
    dim3 tb(32, 8);
    tconvW1_kernel<<<dim3(32, 32, 4), tb, 0, stream>>>(W1, WT);
    tconv_kernel<<<dim3(32, 32, 4), tb, 0, stream>>>(W2, (long)H2, W2t, (long)H2, HID, HID);
    tconv_kernel<<<dim3(GHID / 32, HID / 32, 1), tb, 0, stream>>>(gw1, 0, gw1t, 0, HID, GHID);
    swt_kernel<<<dim3(32 * 1024 / 256), 256, 0, stream>>>(sw, swt);
    bias2_kernel<<<dim3(4 * 2048 / 256), 256, 0, stream>>>(b1, cb);

    // ---- h0 ----
    proj_kernel<<<dim3(HID / 256, NN), 256, 0, stream>>>(x, pw, hb);

    dim3 gfused(2048 / 128, (NN + 127) / 128);  // (16, 79)
    dim3 gw2g(HID / 128, (NN + 127) / 128);     // (8, 79)
    for (int l = 0; l < NLAYERS; ++l) {
        // CB = hb @ [Wd ; Wb]^T + [b1 ; 0]   (N = 2048, fused Cn/Bn)
        mgemm_kernel<0, 1, 0, 0, 1><<<gfused, 256, 0, stream>>>(
            hb, WT + (size_t)l * 2 * H2, nullptr, CB, cb + l * 2048, nullptr, NN, 2048, HID);
        // S = segment_sum(relu(Cn[dst]+Bn[src]))
        gather_kernel<<<dim3(NN), 256, 0, stream>>>(offs, esrc, CB, Sb);
        // h = relu(S @ W2 + deg*b2); last layer also writes fp32 h to d_out
        if (l < NLAYERS - 1)
            mgemm_kernel<1, 1, 1, 0, 1><<<gw2g, 256, 0, stream>>>(
                Sb, W2t + (size_t)l * H2, nullptr, hb, b2 + (size_t)l * HID, degF, NN, HID, HID);
        else
            mgemm_kernel<1, 1, 1, 1, 1><<<gw2g, 256, 0, stream>>>(
                Sb, W2t + (size_t)l * H2, h, hb, b2 + (size_t)l * HID, degF, NN, HID, HID);
    }

    // ---- ghost head ----
    mgemm_kernel<1, 1, 0, 1, 0><<<dim3(GHID / 128, (NN + 127) / 128), 256, 0, stream>>>(
        hb, gw1t, g1, nullptr, gb1, nullptr, NN, GHID, HID);
    ghost_kernel<<<dim3(NN), 256, 0, stream>>>(g1, gw2, gb2, ghost);
    // ---- stable head (MFMA, 1 wave / 16 rows) ----
    stable_mfma_kernel<<<dim3(NN / 16), 64, 0, stream>>>(hb, swt, sb, stable);
}

// Round 6
// 777.297 us; speedup vs baseline: 1.2427x; 1.2427x over previous
//
#include <hip/hip_runtime.h>
#include <hip/hip_bf16.h>
#include <math.h>

#define NN 10000
#define EE 80000
#define SDIM 18
#define HID 1024
#define NLAYERS 4
#define GHID 256

typedef __bf16 bf16;
typedef __bf16 bf16x8 __attribute__((ext_vector_type(8)));
typedef __bf16 bf16x4 __attribute__((ext_vector_type(4)));
typedef float f32x4 __attribute__((ext_vector_type(4)));

#define AS1C(p) ((const __attribute__((address_space(1))) void*)(p))
#define AS3(p)  ((__attribute__((address_space(3))) void*)(p))

// ---------------- zero fill (ints) ----------------
__global__ void zeroi_kernel(int* __restrict__ p, int n) {
    int i = blockIdx.x * 256 + threadIdx.x;
    if (i < n) p[i] = 0;
}

// ---------------- CSR build: count ----------------
__global__ void count_kernel(const int* __restrict__ ei, int* __restrict__ cnt) {
    int e = blockIdx.x * 256 + threadIdx.x;
    if (e < EE) atomicAdd(&cnt[ei[EE + e]], 1);
}

// ---------------- CSR build: exclusive scan (single block) ----------------
__global__ __launch_bounds__(256) void scan_kernel(const int* __restrict__ cnt,
                                                   int* __restrict__ offs,
                                                   int* __restrict__ cursor,
                                                   float* __restrict__ degF) {
    const int CH = 40;  // 256*40 = 10240 >= NN
    __shared__ int partial[256];
    int t = threadIdx.x;
    int base = t * CH;
    int local[CH];
    int sum = 0;
#pragma unroll
    for (int i = 0; i < CH; ++i) {
        int idx = base + i;
        int v = (idx < NN) ? cnt[idx] : 0;
        local[i] = sum;
        sum += v;
    }
    partial[t] = sum;
    __syncthreads();
    for (int off = 1; off < 256; off <<= 1) {
        int v = (t >= off) ? partial[t - off] : 0;
        __syncthreads();
        partial[t] += v;
        __syncthreads();
    }
    int excl = (t == 0) ? 0 : partial[t - 1];
#pragma unroll
    for (int i = 0; i < CH; ++i) {
        int idx = base + i;
        if (idx < NN) {
            int o = excl + local[i];
            offs[idx] = o;
            cursor[idx] = o;
            degF[idx] = (float)cnt[idx];
        }
    }
    if (t == 255) offs[NN] = partial[255];
}

// ---------------- CSR build: scatter edge sources ----------------
__global__ void scatter_kernel(const int* __restrict__ ei, int* __restrict__ cursor,
                               int* __restrict__ esrc) {
    int e = blockIdx.x * 256 + threadIdx.x;
    if (e < EE) {
        int dst = ei[EE + e];
        int pos = atomicAdd(&cursor[dst], 1);
        esrc[pos] = ei[e];
    }
}

// ---------------- fused W1 transpose: WT[l] = [(W1top-W1bot)^T ; W1bot^T] bf16 ----------------
__global__ __launch_bounds__(256) void tconvW1_kernel(const float* __restrict__ W1,
                                                      bf16* __restrict__ WT) {
    __shared__ float td[32][33];
    __shared__ float tb[32][33];
    const size_t H2 = (size_t)HID * HID;
    const float* s = W1 + (size_t)blockIdx.z * 2 * H2;
    bf16* d = WT + (size_t)blockIdx.z * 2 * H2;
    int bx = blockIdx.x * 32;  // col (n) base
    int by = blockIdx.y * 32;  // row (k) base
    int tx = threadIdx.x, ty = threadIdx.y;  // (32,8)
#pragma unroll
    for (int r = 0; r < 4; ++r) {
        int row = by + ty + r * 8;
        float vt = s[(size_t)row * HID + bx + tx];
        float vb = s[H2 + (size_t)row * HID + bx + tx];
        td[ty + r * 8][tx] = vt - vb;
        tb[ty + r * 8][tx] = vb;
    }
    __syncthreads();
#pragma unroll
    for (int r = 0; r < 4; ++r) {
        int orow = bx + ty + r * 8;  // n index
        d[(size_t)orow * HID + by + tx] = (bf16)td[tx][ty + r * 8];
        d[(size_t)(HID + orow) * HID + by + tx] = (bf16)tb[tx][ty + r * 8];
    }
}

// ---------------- generic transpose+convert: dst[N][M] bf16 = src[M][N] fp32 ----------------
__global__ __launch_bounds__(256) void tconv_kernel(const float* __restrict__ src, long sstride,
                                                    bf16* __restrict__ dst, long dstride,
                                                    int M, int N) {
    __shared__ float t[32][33];
    const float* s = src + (size_t)blockIdx.z * sstride;
    bf16* d = dst + (size_t)blockIdx.z * dstride;
    int bx = blockIdx.x * 32;
    int by = blockIdx.y * 32;
    int tx = threadIdx.x, ty = threadIdx.y;
#pragma unroll
    for (int r = 0; r < 4; ++r) {
        int row = by + ty + r * 8;
        t[ty + r * 8][tx] = s[(size_t)row * N + bx + tx];
    }
    __syncthreads();
#pragma unroll
    for (int r = 0; r < 4; ++r) {
        int orow = bx + ty + r * 8;
        d[(size_t)orow * M + by + tx] = (bf16)t[tx][ty + r * 8];
    }
}

// ---------------- swt[32][1024] bf16 = sw[1024][18]^T zero-padded ----------------
__global__ void swt_kernel(const float* __restrict__ sw, bf16* __restrict__ swt) {
    int i = blockIdx.x * 256 + threadIdx.x;  // 32*1024
    int n = i >> 10, k = i & 1023;
    swt[i] = (bf16)(n < SDIM ? sw[k * SDIM + n] : 0.f);
}

// ---------------- combined bias cb[l][2048] = [b1[l] ; 0] ----------------
__global__ void bias2_kernel(const float* __restrict__ b1, float* __restrict__ cb) {
    int i = blockIdx.x * 256 + threadIdx.x;  // 4*2048
    int l = i >> 11, c = i & 2047;
    cb[i] = (c < HID) ? b1[l * HID + c] : 0.f;
}

// ---------------- h0 = sin(x@pw)*cos(x@pw) -> bf16 ----------------
__global__ __launch_bounds__(256) void proj_kernel(const float* __restrict__ x,
                                                   const float* __restrict__ pw,
                                                   bf16* __restrict__ hb) {
    int row = blockIdx.y;
    int col = blockIdx.x * 256 + threadIdx.x;
    __shared__ float xr[SDIM];
    if (threadIdx.x < SDIM) xr[threadIdx.x] = x[row * SDIM + threadIdx.x];
    __syncthreads();
    float acc = 0.f;
#pragma unroll
    for (int k = 0; k < SDIM; ++k) acc += xr[k] * pw[k * HID + col];
    hb[(size_t)row * HID + col] = (bf16)(sinf(acc) * cosf(acc));
}

// ---------------- bf16 MFMA GEMM: C = act(A @ Bt^T + rs*bias) ----------------
// Round-4 staging layout (64B-contiguous slot map, row-major [row][32] planes),
// BK=64 as TWO BK=32 sub-planes per barrier pair (32 MFMA/barrier), GROUP_M=8 swizzle.
template <int RELU, int HAS_BIAS, int HAS_RS, int WF32, int WB16>
__global__ __launch_bounds__(256) void mgemm_kernel(const bf16* __restrict__ A,
                                                    const bf16* __restrict__ Bt,
                                                    float* __restrict__ C,
                                                    bf16* __restrict__ Cb,
                                                    const float* __restrict__ bias,
                                                    const float* __restrict__ rowscale,
                                                    int M, int N, int K) {
    __shared__ bf16 As[2 * 128 * 32];  // two 8KB planes (k-halves)
    __shared__ bf16 Bs[2 * 128 * 32];
    const int tid = threadIdx.x;

    // ---- grouped block swizzle: 8 row-tiles per column sweep ----
    const int num_n = gridDim.x, num_m = gridDim.y;
    int bid = blockIdx.x + blockIdx.y * num_n;
    const int GROUP = 8;
    int width = GROUP * num_n;
    int group = bid / width;
    int rem = bid - group * width;
    int rows_ing = num_m - group * GROUP;
    rows_ing = rows_ing < GROUP ? rows_ing : GROUP;
    int by = group * GROUP + rem % rows_ing;
    int bx = rem / rows_ing;
    const int m0 = by * 128;
    const int n0 = bx * 128;

    const int wave = tid >> 6;
    const int wr = (wave >> 1) * 64, wc = (wave & 1) * 64;
    const int lane = tid & 63;
    const int quad = lane >> 4, r15 = lane & 15;

    f32x4 acc[4][4] = {};

    // staging slots (round-4 map): slot s in [0,512): tile-row s>>2, 16B kseg s&3
    const int s0 = tid, s1 = 256 + tid;
    int ar0 = m0 + (s0 >> 2); ar0 = ar0 < M ? ar0 : M - 1;
    int ar1 = m0 + (s1 >> 2); ar1 = ar1 < M ? ar1 : M - 1;
    const bf16* ga0 = A + (size_t)ar0 * K + (s0 & 3) * 8;
    const bf16* ga1 = A + (size_t)ar1 * K + (s1 & 3) * 8;
    const bf16* gb0 = Bt + (size_t)(n0 + (s0 >> 2)) * K + (s0 & 3) * 8;
    const bf16* gb1 = Bt + (size_t)(n0 + (s1 >> 2)) * K + (s1 & 3) * 8;
    // wave-uniform LDS bases (HW adds lane*16B); +4096 elems = plane 1 (k-half 1)
    bf16* lA0 = As + (size_t)(tid & ~63) * 8;
    bf16* lA1 = As + (size_t)(256 + (tid & ~63)) * 8;
    bf16* lB0 = Bs + (size_t)(tid & ~63) * 8;
    bf16* lB1 = Bs + (size_t)(256 + (tid & ~63)) * 8;

    for (int k0 = 0; k0 < K; k0 += 64) {
        __syncthreads();
        __builtin_amdgcn_global_load_lds(AS1C(ga0 + k0), AS3(lA0), 16, 0, 0);
        __builtin_amdgcn_global_load_lds(AS1C(ga1 + k0), AS3(lA1), 16, 0, 0);
        __builtin_amdgcn_global_load_lds(AS1C(ga0 + k0 + 32), AS3(lA0 + 4096), 16, 0, 0);
        __builtin_amdgcn_global_load_lds(AS1C(ga1 + k0 + 32), AS3(lA1 + 4096), 16, 0, 0);
        __builtin_amdgcn_global_load_lds(AS1C(gb0 + k0), AS3(lB0), 16, 0, 0);
        __builtin_amdgcn_global_load_lds(AS1C(gb1 + k0), AS3(lB1), 16, 0, 0);
        __builtin_amdgcn_global_load_lds(AS1C(gb0 + k0 + 32), AS3(lB0 + 4096), 16, 0, 0);
        __builtin_amdgcn_global_load_lds(AS1C(gb1 + k0 + 32), AS3(lB1 + 4096), 16, 0, 0);
        __syncthreads();
#pragma unroll
        for (int hf = 0; hf < 2; ++hf) {
            bf16x8 af[4], bfr[4];
#pragma unroll
            for (int i = 0; i < 4; ++i)
                af[i] = *(const bf16x8*)(As + hf * 4096 + (wr + i * 16 + r15) * 32 + quad * 8);
#pragma unroll
            for (int j = 0; j < 4; ++j)
                bfr[j] = *(const bf16x8*)(Bs + hf * 4096 + (wc + j * 16 + r15) * 32 + quad * 8);
#pragma unroll
            for (int i = 0; i < 4; ++i)
#pragma unroll
                for (int j = 0; j < 4; ++j)
                    acc[i][j] = __builtin_amdgcn_mfma_f32_16x16x32_bf16(af[i], bfr[j], acc[i][j], 0, 0, 0);
        }
    }

    // epilogue: C/D layout col=lane&15, row=quad*4+reg (m89-verified)
#pragma unroll
    for (int i = 0; i < 4; ++i) {
#pragma unroll
        for (int r = 0; r < 4; ++r) {
            int grow = m0 + wr + i * 16 + quad * 4 + r;
            if (grow >= M) continue;
            float rs = HAS_RS ? rowscale[grow] : 1.f;
#pragma unroll
            for (int j = 0; j < 4; ++j) {
                int gcol = n0 + wc + j * 16 + r15;
                float v = acc[i][j][r];
                if (HAS_BIAS) v += rs * bias[gcol];
                if (RELU) v = fmaxf(v, 0.f);
                if (WF32) C[(size_t)grow * N + gcol] = v;
                if (WB16) Cb[(size_t)grow * N + gcol] = (bf16)v;
            }
        }
    }
}

// ---------------- CSR aggregation over combined CB[node][2048] = [Cn ; Bn] ----------------
__global__ __launch_bounds__(256) void gather_kernel(const int* __restrict__ offs,
                                                     const int* __restrict__ esrc,
                                                     const bf16* __restrict__ CB,
                                                     bf16* __restrict__ Sb) {
    int node = blockIdx.x;
    int c = threadIdx.x * 4;
    int k0 = offs[node], k1 = offs[node + 1];
    bf16x4 cv = *(const bf16x4*)(CB + (size_t)node * 2048 + c);
    float cx = (float)cv.x, cy = (float)cv.y, cz = (float)cv.z, cw = (float)cv.w;
    float ax = 0.f, ay = 0.f, az = 0.f, aw = 0.f;
    for (int k = k0; k < k1; ++k) {
        int s = esrc[k];
        bf16x4 bv = *(const bf16x4*)(CB + (size_t)s * 2048 + 1024 + c);
        ax += fmaxf(cx + (float)bv.x, 0.f);
        ay += fmaxf(cy + (float)bv.y, 0.f);
        az += fmaxf(cz + (float)bv.z, 0.f);
        aw += fmaxf(cw + (float)bv.w, 0.f);
    }
    bf16x4 o;
    o.x = (bf16)ax; o.y = (bf16)ay; o.z = (bf16)az; o.w = (bf16)aw;
    *(bf16x4*)(Sb + (size_t)node * HID + c) = o;
}

// ---------------- stable head via MFMA: out[16 rows][18] = hb_tile @ swt^T + sb ----------------
__global__ __launch_bounds__(64) void stable_mfma_kernel(const bf16* __restrict__ hb,
                                                         const bf16* __restrict__ swt,
                                                         const float* __restrict__ sb,
                                                         float* __restrict__ out) {
    int m0 = blockIdx.x * 16;  // NN = 625*16 exact
    int lane = threadIdx.x;
    int quad = lane >> 4, r15 = lane & 15;
    f32x4 acc0 = {}, acc1 = {};
    const bf16* arow = hb + (size_t)(m0 + r15) * HID + quad * 8;
    const bf16* b0 = swt + (size_t)r15 * HID + quad * 8;
    const bf16* b1p = swt + (size_t)(16 + r15) * HID + quad * 8;
    for (int k0 = 0; k0 < HID; k0 += 32) {
        bf16x8 af = *(const bf16x8*)(arow + k0);
        bf16x8 bf0 = *(const bf16x8*)(b0 + k0);
        bf16x8 bf1 = *(const bf16x8*)(b1p + k0);
        acc0 = __builtin_amdgcn_mfma_f32_16x16x32_bf16(af, bf0, acc0, 0, 0, 0);
        acc1 = __builtin_amdgcn_mfma_f32_16x16x32_bf16(af, bf1, acc1, 0, 0, 0);
    }
#pragma unroll
    for (int r = 0; r < 4; ++r) {
        int grow = m0 + quad * 4 + r;
        out[(size_t)grow * SDIM + r15] = acc0[r] + sb[r15];
        if (r15 < 2) out[(size_t)grow * SDIM + 16 + r15] = acc1[r] + sb[16 + r15];
    }
}

// ---------------- ghost head stage 2: sigmoid(g1 @ gw2 + gb2) ----------------
__global__ __launch_bounds__(256) void ghost_kernel(const float* __restrict__ g1,
                                                    const float* __restrict__ gw2,
                                                    const float* __restrict__ gb2,
                                                    float* __restrict__ out) {
    int row = blockIdx.x;
    int t = threadIdx.x;
    float v = g1[(size_t)row * GHID + t] * gw2[t];
#pragma unroll
    for (int o = 32; o > 0; o >>= 1) v += __shfl_down(v, o, 64);
    __shared__ float red[4];
    if ((t & 63) == 0) red[t >> 6] = v;
    __syncthreads();
    if (t == 0) {
        float s = red[0] + red[1] + red[2] + red[3] + gb2[0];
        out[row] = 1.f / (1.f + expf(-s));
    }
}

extern "C" void kernel_launch(void* const* d_in, const int* in_sizes, int n_in,
                              void* d_out, int out_size, void* d_ws, size_t ws_size,
                              hipStream_t stream) {
    const float* x   = (const float*)d_in[0];
    const int*   ei  = (const int*)d_in[1];
    const float* pw  = (const float*)d_in[2];
    const float* W1  = (const float*)d_in[3];
    const float* b1  = (const float*)d_in[4];
    const float* W2  = (const float*)d_in[5];
    const float* b2  = (const float*)d_in[6];
    const float* gw1 = (const float*)d_in[7];
    const float* gb1 = (const float*)d_in[8];
    const float* gw2 = (const float*)d_in[9];
    const float* gb2 = (const float*)d_in[10];
    const float* sw  = (const float*)d_in[11];
    const float* sb  = (const float*)d_in[12];

    float* out    = (float*)d_out;
    float* ghost  = out;                  // [N,1]
    float* stable = out + NN;             // [N,18]
    float* h      = out + NN + NN * SDIM; // [N,HID] fp32 (final h output)

    const size_t H2 = (size_t)HID * HID;
    float* ws   = (float*)d_ws;
    float* g1   = ws;                                  // NN*GHID fp32
    float* degF = g1 + (size_t)NN * GHID;              // NN
    float* cb   = degF + NN;                           // 4*2048 fp32
    bf16* hb    = (bf16*)(cb + 4 * 2048);              // NN*HID
    bf16* Sb    = hb + (size_t)NN * HID;               // NN*HID
    bf16* CB    = Sb + (size_t)NN * HID;               // NN*2048
    bf16* WT    = CB + (size_t)NN * 2048;              // 4 * 2*H2  ([Wd;Wb]^T per layer)
    bf16* W2t   = WT + 8 * H2;                         // 4*H2
    bf16* gw1t  = W2t + 4 * H2;                        // GHID*HID
    bf16* swt   = gw1t + (size_t)GHID * HID;           // 32*1024
    int*  cnt    = (int*)(swt + 32 * 1024);
    int*  offs   = cnt + NN;
    int*  cursor = offs + NN + 1;
    int*  esrc   = cursor + NN;

    // ---- CSR build ----
    zeroi_kernel<<<dim3((NN + 255) / 256), 256, 0, stream>>>(cnt, NN);
    count_kernel<<<dim3((EE + 255) / 256), 256, 0, stream>>>(ei, cnt);
    scan_kernel<<<dim3(1), 256, 0, stream>>>(cnt, offs, cursor, degF);
    scatter_kernel<<<dim3((EE + 255) / 256), 256, 0, stream>>>(ei, cursor, esrc);

    // ---- weight prep ----
    dim3 tb(32, 8);
    tconvW1_kernel<<<dim3(32, 32, 4), tb, 0, stream>>>(W1, WT);
    tconv_kernel<<<dim3(32, 32, 4), tb, 0, stream>>>(W2, (long)H2, W2t, (long)H2, HID, HID);
    tconv_kernel<<<dim3(GHID / 32, HID / 32, 1), tb, 0, stream>>>(gw1, 0, gw1t, 0, HID, GHID);
    swt_kernel<<<dim3(32 * 1024 / 256), 256, 0, stream>>>(sw, swt);
    bias2_kernel<<<dim3(4 * 2048 / 256), 256, 0, stream>>>(b1, cb);

    // ---- h0 ----
    proj_kernel<<<dim3(HID / 256, NN), 256, 0, stream>>>(x, pw, hb);

    dim3 gfused(2048 / 128, (NN + 127) / 128);  // (16, 79)
    dim3 gw2g(HID / 128, (NN + 127) / 128);     // (8, 79)
    for (int l = 0; l < NLAYERS; ++l) {
        // CB = hb @ [Wd ; Wb]^T + [b1 ; 0]   (N = 2048, fused Cn/Bn)
        mgemm_kernel<0, 1, 0, 0, 1><<<gfused, 256, 0, stream>>>(
            hb, WT + (size_t)l * 2 * H2, nullptr, CB, cb + l * 2048, nullptr, NN, 2048, HID);
        // S = segment_sum(relu(Cn[dst]+Bn[src]))
        gather_kernel<<<dim3(NN), 256, 0, stream>>>(offs, esrc, CB, Sb);
        // h = relu(S @ W2 + deg*b2); last layer also writes fp32 h to d_out
        if (l < NLAYERS - 1)
            mgemm_kernel<1, 1, 1, 0, 1><<<gw2g, 256, 0, stream>>>(
                Sb, W2t + (size_t)l * H2, nullptr, hb, b2 + (size_t)l * HID, degF, NN, HID, HID);
        else
            mgemm_kernel<1, 1, 1, 1, 1><<<gw2g, 256, 0, stream>>>(
                Sb, W2t + (size_t)l * H2, h, hb, b2 + (size_t)l * HID, degF, NN, HID, HID);
    }

    // ---- ghost head ----
    mgemm_kernel<1, 1, 0, 1, 0><<<dim3(GHID / 128, (NN + 127) / 128), 256, 0, stream>>>(
        hb, gw1t, g1, nullptr, gb1, nullptr, NN, GHID, HID);
    ghost_kernel<<<dim3(NN), 256, 0, stream>>>(g1, gw2, gb2, ghost);
    // ---- stable head (MFMA, 1 wave / 16 rows) ----
    stable_mfma_kernel<<<dim3(NN / 16), 64, 0, stream>>>(hb, swt, sb, stable);
}

// Round 7
// 750.754 us; speedup vs baseline: 1.2866x; 1.0354x over previous
//
#include <hip/hip_runtime.h>
#include <hip/hip_bf16.h>
#include <math.h>

#define NN 10000
#define EE 80000
#define SDIM 18
#define HID 1024
#define NLAYERS 4
#define GHID 256

typedef __bf16 bf16;
typedef __bf16 bf16x8 __attribute__((ext_vector_type(8)));
typedef __bf16 bf16x4 __attribute__((ext_vector_type(4)));
typedef float f32x4 __attribute__((ext_vector_type(4)));

#define AS1C(p) ((const __attribute__((address_space(1))) void*)(p))
#define AS3(p)  ((__attribute__((address_space(3))) void*)(p))

// ---------------- CSR build: count ----------------
__global__ void count_kernel(const int* __restrict__ ei, int* __restrict__ cnt) {
    int e = blockIdx.x * 256 + threadIdx.x;
    if (e < EE) atomicAdd(&cnt[ei[EE + e]], 1);
}

// ---------------- CSR build: exclusive scan (single block) ----------------
__global__ __launch_bounds__(256) void scan_kernel(const int* __restrict__ cnt,
                                                   int* __restrict__ offs,
                                                   int* __restrict__ cursor,
                                                   float* __restrict__ degF) {
    const int CH = 40;  // 256*40 = 10240 >= NN
    __shared__ int partial[256];
    int t = threadIdx.x;
    int base = t * CH;
    int local[CH];
    int sum = 0;
#pragma unroll
    for (int i = 0; i < CH; ++i) {
        int idx = base + i;
        int v = (idx < NN) ? cnt[idx] : 0;
        local[i] = sum;
        sum += v;
    }
    partial[t] = sum;
    __syncthreads();
    for (int off = 1; off < 256; off <<= 1) {
        int v = (t >= off) ? partial[t - off] : 0;
        __syncthreads();
        partial[t] += v;
        __syncthreads();
    }
    int excl = (t == 0) ? 0 : partial[t - 1];
#pragma unroll
    for (int i = 0; i < CH; ++i) {
        int idx = base + i;
        if (idx < NN) {
            int o = excl + local[i];
            offs[idx] = o;
            cursor[idx] = o;
            degF[idx] = (float)cnt[idx];
        }
    }
    if (t == 255) offs[NN] = partial[255];
}

// ---------------- CSR build: scatter edge sources ----------------
__global__ void scatter_kernel(const int* __restrict__ ei, int* __restrict__ cursor,
                               int* __restrict__ esrc) {
    int e = blockIdx.x * 256 + threadIdx.x;
    if (e < EE) {
        int dst = ei[EE + e];
        int pos = atomicAdd(&cursor[dst], 1);
        esrc[pos] = ei[e];
    }
}

// ---------------- fused prep: all weight transposes + swt + cb + cnt-zero ----------------
// blocks [0,4096): W1 -> WT = [(W1top-W1bot)^T ; W1bot^T] per layer
// blocks [4096,8192): W2 -> W2t
// blocks [8192,8448): gw1 -> gw1t
// blocks [8448,8576): swt
// blocks [8576,8608): cb
// blocks [8608,8648): cnt zero
__global__ __launch_bounds__(256) void prep_kernel(const float* __restrict__ W1,
                                                   const float* __restrict__ W2,
                                                   const float* __restrict__ gw1,
                                                   const float* __restrict__ sw,
                                                   const float* __restrict__ b1,
                                                   bf16* __restrict__ WT,
                                                   bf16* __restrict__ W2t,
                                                   bf16* __restrict__ gw1t,
                                                   bf16* __restrict__ swt,
                                                   float* __restrict__ cb,
                                                   int* __restrict__ cnt) {
    __shared__ float td[32][33];
    __shared__ float tb[32][33];
    const size_t H2 = (size_t)HID * HID;
    int b = blockIdx.x;
    int tx = threadIdx.x & 31, ty = threadIdx.x >> 5;  // (32,8)

    if (b < 4096) {  // W1 fused diff transpose
        int l = b >> 10, r = b & 1023;
        int bx = (r & 31) * 32, by = (r >> 5) * 32;
        const float* s = W1 + (size_t)l * 2 * H2;
        bf16* d = WT + (size_t)l * 2 * H2;
#pragma unroll
        for (int r4 = 0; r4 < 4; ++r4) {
            int row = by + ty + r4 * 8;
            float vt = s[(size_t)row * HID + bx + tx];
            float vb = s[H2 + (size_t)row * HID + bx + tx];
            td[ty + r4 * 8][tx] = vt - vb;
            tb[ty + r4 * 8][tx] = vb;
        }
        __syncthreads();
#pragma unroll
        for (int r4 = 0; r4 < 4; ++r4) {
            int orow = bx + ty + r4 * 8;
            d[(size_t)orow * HID + by + tx] = (bf16)td[tx][ty + r4 * 8];
            d[(size_t)(HID + orow) * HID + by + tx] = (bf16)tb[tx][ty + r4 * 8];
        }
    } else if (b < 8192) {  // W2 transpose
        int sub = b - 4096;
        int l = sub >> 10, r = sub & 1023;
        int bx = (r & 31) * 32, by = (r >> 5) * 32;
        const float* s = W2 + (size_t)l * H2;
        bf16* d = W2t + (size_t)l * H2;
#pragma unroll
        for (int r4 = 0; r4 < 4; ++r4) {
            int row = by + ty + r4 * 8;
            td[ty + r4 * 8][tx] = s[(size_t)row * HID + bx + tx];
        }
        __syncthreads();
#pragma unroll
        for (int r4 = 0; r4 < 4; ++r4) {
            int orow = bx + ty + r4 * 8;
            d[(size_t)orow * HID + by + tx] = (bf16)td[tx][ty + r4 * 8];
        }
    } else if (b < 8448) {  // gw1 [1024][256] -> gw1t [256][1024]
        int sub = b - 8192;
        int bx = (sub & 7) * 32, by = (sub >> 3) * 32;
#pragma unroll
        for (int r4 = 0; r4 < 4; ++r4) {
            int row = by + ty + r4 * 8;
            td[ty + r4 * 8][tx] = gw1[(size_t)row * GHID + bx + tx];
        }
        __syncthreads();
#pragma unroll
        for (int r4 = 0; r4 < 4; ++r4) {
            int orow = bx + ty + r4 * 8;
            gw1t[(size_t)orow * HID + by + tx] = (bf16)td[tx][ty + r4 * 8];
        }
    } else if (b < 8576) {  // swt[32][1024] = sw[1024][18]^T zero-padded
        int i = (b - 8448) * 256 + threadIdx.x;
        int n = i >> 10, k = i & 1023;
        swt[i] = (bf16)(n < SDIM ? sw[k * SDIM + n] : 0.f);
    } else if (b < 8608) {  // cb[l][2048] = [b1[l] ; 0]
        int i = (b - 8576) * 256 + threadIdx.x;
        int l = i >> 11, c = i & 2047;
        cb[i] = (c < HID) ? b1[l * HID + c] : 0.f;
    } else {  // cnt zero
        int i = (b - 8608) * 256 + threadIdx.x;
        if (i < NN) cnt[i] = 0;
    }
}

// ---------------- h0 = sin(x@pw)*cos(x@pw) -> bf16 ----------------
__global__ __launch_bounds__(256) void proj_kernel(const float* __restrict__ x,
                                                   const float* __restrict__ pw,
                                                   bf16* __restrict__ hb) {
    int row = blockIdx.y;
    int col = blockIdx.x * 256 + threadIdx.x;
    __shared__ float xr[SDIM];
    if (threadIdx.x < SDIM) xr[threadIdx.x] = x[row * SDIM + threadIdx.x];
    __syncthreads();
    float acc = 0.f;
#pragma unroll
    for (int k = 0; k < SDIM; ++k) acc += xr[k] * pw[k * HID + col];
    hb[(size_t)row * HID + col] = (bf16)(sinf(acc) * cosf(acc));
}

// ---------------- bf16 MFMA GEMM: C = act(A @ Bt^T + rs*bias) ----------------
// Double-buffered BK=32 K-loop: one barrier/iter, loads for iter k+1 issued
// BEFORE computing on iter k (latency hidden behind MFMA). LDS 32 KB total ->
// 5 blocks/CU. Round-4 coalesced slot map (64B contiguous per 4 lanes).
// GROUP_M=8 swizzle for per-XCD A-tile L2 reuse.
template <int RELU, int HAS_BIAS, int HAS_RS, int WF32, int WB16>
__global__ __launch_bounds__(256) void mgemm_kernel(const bf16* __restrict__ A,
                                                    const bf16* __restrict__ Bt,
                                                    float* __restrict__ C,
                                                    bf16* __restrict__ Cb,
                                                    const float* __restrict__ bias,
                                                    const float* __restrict__ rowscale,
                                                    int M, int N, int K) {
    __shared__ bf16 As[2][128 * 32];
    __shared__ bf16 Bs[2][128 * 32];
    const int tid = threadIdx.x;

    // ---- grouped block swizzle: 8 row-tiles per column sweep ----
    const int num_n = gridDim.x, num_m = gridDim.y;
    int bid = blockIdx.x + blockIdx.y * num_n;
    const int GROUP = 8;
    int width = GROUP * num_n;
    int group = bid / width;
    int rem = bid - group * width;
    int rows_ing = num_m - group * GROUP;
    rows_ing = rows_ing < GROUP ? rows_ing : GROUP;
    int by = group * GROUP + rem % rows_ing;
    int bx = rem / rows_ing;
    const int m0 = by * 128;
    const int n0 = bx * 128;

    const int wave = tid >> 6;
    const int wr = (wave >> 1) * 64, wc = (wave & 1) * 64;
    const int lane = tid & 63;
    const int quad = lane >> 4, r15 = lane & 15;

    f32x4 acc[4][4] = {};

    // staging slots: slot s in [0,512): tile-row s>>2, 16B kseg s&3
    const int s0 = tid, s1 = 256 + tid;
    int ar0 = m0 + (s0 >> 2); ar0 = ar0 < M ? ar0 : M - 1;
    int ar1 = m0 + (s1 >> 2); ar1 = ar1 < M ? ar1 : M - 1;
    const bf16* ga0 = A + (size_t)ar0 * K + (s0 & 3) * 8;
    const bf16* ga1 = A + (size_t)ar1 * K + (s1 & 3) * 8;
    const bf16* gb0 = Bt + (size_t)(n0 + (s0 >> 2)) * K + (s0 & 3) * 8;
    const bf16* gb1 = Bt + (size_t)(n0 + (s1 >> 2)) * K + (s1 & 3) * 8;
    // wave-uniform LDS offsets (HW adds lane*16B)
    const int lofs0 = (tid & ~63) * 8;
    const int lofs1 = 2048 + (tid & ~63) * 8;

    // prologue: stage iter 0 into buf 0
    __builtin_amdgcn_global_load_lds(AS1C(ga0), AS3(&As[0][lofs0]), 16, 0, 0);
    __builtin_amdgcn_global_load_lds(AS1C(ga1), AS3(&As[0][lofs1]), 16, 0, 0);
    __builtin_amdgcn_global_load_lds(AS1C(gb0), AS3(&Bs[0][lofs0]), 16, 0, 0);
    __builtin_amdgcn_global_load_lds(AS1C(gb1), AS3(&Bs[0][lofs1]), 16, 0, 0);

    const int NIT = K >> 5;
    for (int k = 0; k < NIT; ++k) {
        const int buf = k & 1;
        // barrier: (a) vmcnt drain -> buf fully staged (issued one iter ago),
        //          (b) lgkm drain -> all waves' ds_reads of buf^1 finished.
        __syncthreads();
        if (k + 1 < NIT) {  // issue next tile's staging BEFORE compute
            const int ko = (k + 1) << 5;
            __builtin_amdgcn_global_load_lds(AS1C(ga0 + ko), AS3(&As[buf ^ 1][lofs0]), 16, 0, 0);
            __builtin_amdgcn_global_load_lds(AS1C(ga1 + ko), AS3(&As[buf ^ 1][lofs1]), 16, 0, 0);
            __builtin_amdgcn_global_load_lds(AS1C(gb0 + ko), AS3(&Bs[buf ^ 1][lofs0]), 16, 0, 0);
            __builtin_amdgcn_global_load_lds(AS1C(gb1 + ko), AS3(&Bs[buf ^ 1][lofs1]), 16, 0, 0);
        }
        bf16x8 af[4], bfr[4];
#pragma unroll
        for (int i = 0; i < 4; ++i)
            af[i] = *(const bf16x8*)(&As[buf][(wr + i * 16 + r15) * 32 + quad * 8]);
#pragma unroll
        for (int j = 0; j < 4; ++j)
            bfr[j] = *(const bf16x8*)(&Bs[buf][(wc + j * 16 + r15) * 32 + quad * 8]);
#pragma unroll
        for (int i = 0; i < 4; ++i)
#pragma unroll
            for (int j = 0; j < 4; ++j)
                acc[i][j] = __builtin_amdgcn_mfma_f32_16x16x32_bf16(af[i], bfr[j], acc[i][j], 0, 0, 0);
    }

    // epilogue: C/D layout col=lane&15, row=quad*4+reg (m89-verified)
#pragma unroll
    for (int i = 0; i < 4; ++i) {
#pragma unroll
        for (int r = 0; r < 4; ++r) {
            int grow = m0 + wr + i * 16 + quad * 4 + r;
            if (grow >= M) continue;
            float rs = HAS_RS ? rowscale[grow] : 1.f;
#pragma unroll
            for (int j = 0; j < 4; ++j) {
                int gcol = n0 + wc + j * 16 + r15;
                float v = acc[i][j][r];
                if (HAS_BIAS) v += rs * bias[gcol];
                if (RELU) v = fmaxf(v, 0.f);
                if (WF32) C[(size_t)grow * N + gcol] = v;
                if (WB16) Cb[(size_t)grow * N + gcol] = (bf16)v;
            }
        }
    }
}

// ---------------- CSR aggregation over CB[node][2048] = [Cn ; Bn] ----------------
// 2 nodes/block; 128 threads x bf16x8 (16B/lane) per node.
__global__ __launch_bounds__(256) void gather_kernel(const int* __restrict__ offs,
                                                     const int* __restrict__ esrc,
                                                     const bf16* __restrict__ CB,
                                                     bf16* __restrict__ Sb) {
    int half = threadIdx.x >> 7;
    int t = threadIdx.x & 127;
    int node = blockIdx.x * 2 + half;
    int c = t * 8;
    int k0 = offs[node], k1 = offs[node + 1];
    bf16x8 cv = *(const bf16x8*)(CB + (size_t)node * 2048 + c);
    float cf[8], a[8];
#pragma unroll
    for (int i = 0; i < 8; ++i) { cf[i] = (float)cv[i]; a[i] = 0.f; }
    for (int k = k0; k < k1; ++k) {
        int s = esrc[k];
        bf16x8 bv = *(const bf16x8*)(CB + (size_t)s * 2048 + 1024 + c);
#pragma unroll
        for (int i = 0; i < 8; ++i) a[i] += fmaxf(cf[i] + (float)bv[i], 0.f);
    }
    bf16x8 o;
#pragma unroll
    for (int i = 0; i < 8; ++i) o[i] = (bf16)a[i];
    *(bf16x8*)(Sb + (size_t)node * HID + c) = o;
}

// ---------------- stable head via MFMA: out[16 rows][18] = hb_tile @ swt^T + sb ----------------
__global__ __launch_bounds__(64) void stable_mfma_kernel(const bf16* __restrict__ hb,
                                                         const bf16* __restrict__ swt,
                                                         const float* __restrict__ sb,
                                                         float* __restrict__ out) {
    int m0 = blockIdx.x * 16;  // NN = 625*16 exact
    int lane = threadIdx.x;
    int quad = lane >> 4, r15 = lane & 15;
    f32x4 acc0 = {}, acc1 = {};
    const bf16* arow = hb + (size_t)(m0 + r15) * HID + quad * 8;
    const bf16* b0 = swt + (size_t)r15 * HID + quad * 8;
    const bf16* b1p = swt + (size_t)(16 + r15) * HID + quad * 8;
    for (int k0 = 0; k0 < HID; k0 += 32) {
        bf16x8 af = *(const bf16x8*)(arow + k0);
        bf16x8 bf0 = *(const bf16x8*)(b0 + k0);
        bf16x8 bf1 = *(const bf16x8*)(b1p + k0);
        acc0 = __builtin_amdgcn_mfma_f32_16x16x32_bf16(af, bf0, acc0, 0, 0, 0);
        acc1 = __builtin_amdgcn_mfma_f32_16x16x32_bf16(af, bf1, acc1, 0, 0, 0);
    }
#pragma unroll
    for (int r = 0; r < 4; ++r) {
        int grow = m0 + quad * 4 + r;
        out[(size_t)grow * SDIM + r15] = acc0[r] + sb[r15];
        if (r15 < 2) out[(size_t)grow * SDIM + 16 + r15] = acc1[r] + sb[16 + r15];
    }
}

// ---------------- ghost head stage 2: sigmoid(g1 @ gw2 + gb2), wave per row ----------------
__global__ __launch_bounds__(256) void ghost_kernel(const float* __restrict__ g1,
                                                    const float* __restrict__ gw2,
                                                    const float* __restrict__ gb2,
                                                    float* __restrict__ out) {
    int w = threadIdx.x >> 6, lane = threadIdx.x & 63;
    int row = blockIdx.x * 4 + w;  // NN = 2500*4 exact
    const float4 gv = *(const float4*)(g1 + (size_t)row * GHID + lane * 4);
    const float4 wv = *(const float4*)(gw2 + lane * 4);
    float v = gv.x * wv.x + gv.y * wv.y + gv.z * wv.z + gv.w * wv.w;
#pragma unroll
    for (int o = 32; o > 0; o >>= 1) v += __shfl_down(v, o, 64);
    if (lane == 0) out[row] = 1.f / (1.f + expf(-(v + gb2[0])));
}

extern "C" void kernel_launch(void* const* d_in, const int* in_sizes, int n_in,
                              void* d_out, int out_size, void* d_ws, size_t ws_size,
                              hipStream_t stream) {
    const float* x   = (const float*)d_in[0];
    const int*   ei  = (const int*)d_in[1];
    const float* pw  = (const float*)d_in[2];
    const float* W1  = (const float*)d_in[3];
    const float* b1  = (const float*)d_in[4];
    const float* W2  = (const float*)d_in[5];
    const float* b2  = (const float*)d_in[6];
    const float* gw1 = (const float*)d_in[7];
    const float* gb1 = (const float*)d_in[8];
    const float* gw2 = (const float*)d_in[9];
    const float* gb2 = (const float*)d_in[10];
    const float* sw  = (const float*)d_in[11];
    const float* sb  = (const float*)d_in[12];

    float* out    = (float*)d_out;
    float* ghost  = out;                  // [N,1]
    float* stable = out + NN;             // [N,18]
    float* h      = out + NN + NN * SDIM; // [N,HID] fp32 (final h output)

    const size_t H2 = (size_t)HID * HID;
    float* ws   = (float*)d_ws;
    float* g1   = ws;                                  // NN*GHID fp32
    float* degF = g1 + (size_t)NN * GHID;              // NN
    float* cb   = degF + NN;                           // 4*2048 fp32
    bf16* hb    = (bf16*)(cb + 4 * 2048);              // NN*HID
    bf16* Sb    = hb + (size_t)NN * HID;               // NN*HID
    bf16* CB    = Sb + (size_t)NN * HID;               // NN*2048
    bf16* WT    = CB + (size_t)NN * 2048;              // 4 * 2*H2  ([Wd;Wb]^T per layer)
    bf16* W2t   = WT + 8 * H2;                         // 4*H2
    bf16* gw1t  = W2t + 4 * H2;                        // GHID*HID
    bf16* swt   = gw1t + (size_t)GHID * HID;           // 32*1024
    int*  cnt    = (int*)(swt + 32 * 1024);
    int*  offs   = cnt + NN;
    int*  cursor = offs + NN + 1;
    int*  esrc   = cursor + NN;

    // ---- fused prep (weights transpose/convert + swt + cb + cnt zero) ----
    prep_kernel<<<dim3(8648), 256, 0, stream>>>(W1, W2, gw1, sw, b1, WT, W2t, gw1t, swt, cb, cnt);

    // ---- CSR build ----
    count_kernel<<<dim3((EE + 255) / 256), 256, 0, stream>>>(ei, cnt);
    scan_kernel<<<dim3(1), 256, 0, stream>>>(cnt, offs, cursor, degF);
    scatter_kernel<<<dim3((EE + 255) / 256), 256, 0, stream>>>(ei, cursor, esrc);

    // ---- h0 ----
    proj_kernel<<<dim3(HID / 256, NN), 256, 0, stream>>>(x, pw, hb);

    dim3 gfused(2048 / 128, (NN + 127) / 128);  // (16, 79)
    dim3 gw2g(HID / 128, (NN + 127) / 128);     // (8, 79)
    for (int l = 0; l < NLAYERS; ++l) {
        // CB = hb @ [Wd ; Wb]^T + [b1 ; 0]   (N = 2048, fused Cn/Bn)
        mgemm_kernel<0, 1, 0, 0, 1><<<gfused, 256, 0, stream>>>(
            hb, WT + (size_t)l * 2 * H2, nullptr, CB, cb + l * 2048, nullptr, NN, 2048, HID);
        // S = segment_sum(relu(Cn[dst]+Bn[src]))
        gather_kernel<<<dim3(NN / 2), 256, 0, stream>>>(offs, esrc, CB, Sb);
        // h = relu(S @ W2 + deg*b2); last layer also writes fp32 h to d_out
        if (l < NLAYERS - 1)
            mgemm_kernel<1, 1, 1, 0, 1><<<gw2g, 256, 0, stream>>>(
                Sb, W2t + (size_t)l * H2, nullptr, hb, b2 + (size_t)l * HID, degF, NN, HID, HID);
        else
            mgemm_kernel<1, 1, 1, 1, 1><<<gw2g, 256, 0, stream>>>(
                Sb, W2t + (size_t)l * H2, h, hb, b2 + (size_t)l * HID, degF, NN, HID, HID);
    }

    // ---- ghost head ----
    mgemm_kernel<1, 1, 0, 1, 0><<<dim3(GHID / 128, (NN + 127) / 128), 256, 0, stream>>>(
        hb, gw1t, g1, nullptr, gb1, nullptr, NN, GHID, HID);
    ghost_kernel<<<dim3(NN / 4), 256, 0, stream>>>(g1, gw2, gb2, ghost);
    // ---- stable head (MFMA, 1 wave / 16 rows) ----
    stable_mfma_kernel<<<dim3(NN / 16), 64, 0, stream>>>(hb, swt, sb, stable);
}